// Round 2
// baseline (1718.193 us; speedup 1.0000x reference)
//
#include <hip/hip_runtime.h>
#include <math.h>

namespace {

constexpr int kB = 2, kH = 16, kN = 8192, kHD = 128, kJ = 20;
constexpr int kTQ = 64;                         // queries per 256-thread block (4 lanes/query)
constexpr int kNT = kN / kTQ;                   // 128 n-tiles per (b,h)
constexpr int kNWG = kB * kH * kNT;             // 4096 workgroups
constexpr int kNXCD = 8;
constexpr int kChunk = kNWG / kNXCD;            // 512 contiguous blocks per XCD
constexpr float kScale = 0.08838834764831845f;  // 1/sqrt(128)

// Native clang vector type — required for __builtin_nontemporal_{load,store}
// (HIP_vector_type float4 is a struct and the builtin rejects it).
typedef float f4 __attribute__((ext_vector_type(4)));

// Lane mapping: t>>2 = query, t&3 = part. Lane `part` owns float4 chunks
// {i*4 + part : i in 0..7} — each wave-level load instruction covers a
// CONTIGUOUS 64B span per 4-lane group (minimum cache lines/instr).
//
// XCD swizzle: the dispatcher round-robins linear block ids across 8 XCDs.
// Without remap, consecutive n-tiles of one (b,h) slice land on different
// XCDs -> the 1024-row gather lookback always misses the 4MiB per-XCD L2
// and the ~256MiB concurrent footprint thrashes L3 (measured 1.26GB FETCH
// vs 200MB ideal). Remap so XCD x gets the contiguous id range
// [x*512, (x+1)*512): 4 whole (b,h) slices, ascending n -> sliding-window
// reuse hits L2/L3. Bijection: lin in [0,4096), swz=(lin&7)*512+(lin>>3).
__global__ __launch_bounds__(256, 8)
void dsqg_fwd(const float* __restrict__ q, const float* __restrict__ k,
              const float* __restrict__ v, const float* __restrict__ pb,
              const float* __restrict__ se, float* __restrict__ out) {
  constexpr int OFFS[kJ] = {1, 2, 3, 4, 5, 6, 7, 8, 9, 11,
                            13, 15, 16, 23, 32, 64, 128, 256, 512, 1024};
  __shared__ float s_se[kJ * kHD];  // 10 KB
  __shared__ float s_pb[kJ];

  const int t = threadIdx.x;
  const int lin = blockIdx.x;
  const int swz = (lin & (kNXCD - 1)) * kChunk + (lin >> 3);
  const int bh = swz >> 7;                  // swz / kNT
  const int ntile = swz & (kNT - 1);
  const int h = bh & (kH - 1);
  const int n = ntile * kTQ + (t >> 2);
  const int part = t & 3;

  for (int i = t; i < kJ * kHD; i += 256) s_se[i] = se[i];
  if (t < kJ) s_pb[t] = pb[t * kH + h];
  __syncthreads();

  const size_t base = (size_t)bh * kN * kHD;
  const f4* qrow = (const f4*)(q + base + (size_t)n * kHD);
  f4 rq[8];
#pragma unroll
  for (int i = 0; i < 8; ++i) rq[i] = __builtin_nontemporal_load(&qrow[i * 4 + part]);

  // ---- Phase A: s_j = sc*(q.(k[n-dj]+se_j)) + pb[j][h], -inf if n<dj
  float sc[kJ];
#pragma unroll
  for (int j = 0; j < kJ; ++j) {
    const int delta = OFFS[j];
    int kr = n - delta;
    kr = kr < 0 ? 0 : kr;
    const f4* krow = (const f4*)(k + base + (size_t)kr * kHD);
    const f4* srow = (const f4*)(s_se + j * kHD);
    float acc = 0.f;
#pragma unroll
    for (int i = 0; i < 8; ++i) {
      f4 kv = krow[i * 4 + part];
      f4 sv = srow[i * 4 + part];
      acc += rq[i].x * (kv.x + sv.x);
      acc += rq[i].y * (kv.y + sv.y);
      acc += rq[i].z * (kv.z + sv.z);
      acc += rq[i].w * (kv.w + sv.w);
    }
    acc += __shfl_xor(acc, 1);
    acc += __shfl_xor(acc, 2);
    const float sj = acc * kScale + s_pb[j];
    sc[j] = (n >= delta) ? sj : -INFINITY;
  }

  // ---- softmax over J (redundant in the 4 lanes)
  float m = -INFINITY;
#pragma unroll
  for (int j = 0; j < kJ; ++j) m = fmaxf(m, sc[j]);
  const float msafe = (m == -INFINITY) ? 0.f : m;
  float l = 0.f;
#pragma unroll
  for (int j = 0; j < kJ; ++j) {
    const float e = (sc[j] == -INFINITY) ? 0.f : __expf(sc[j] - msafe);
    sc[j] = e;  // reuse: sc now holds unnormalized p
    l += e;
  }
  const float inv = (l > 0.f) ? 1.f / l : 0.f;  // n==0 -> zero output

  // ---- Phase B: out = sum_j p_j * v[n-dj]
  f4 o[8];
#pragma unroll
  for (int i = 0; i < 8; ++i) o[i] = (f4)(0.f);
#pragma unroll
  for (int j = 0; j < kJ; ++j) {
    const float pj = sc[j] * inv;
    int vr = n - OFFS[j];
    vr = vr < 0 ? 0 : vr;
    const f4* vrow = (const f4*)(v + base + (size_t)vr * kHD);
#pragma unroll
    for (int i = 0; i < 8; ++i) {
      f4 vv = vrow[i * 4 + part];
      o[i] += pj * vv;
    }
  }
  f4* orow = (f4*)(out + base + (size_t)n * kHD);
#pragma unroll
  for (int i = 0; i < 8; ++i) __builtin_nontemporal_store(o[i], &orow[i * 4 + part]);
}

}  // namespace

extern "C" void kernel_launch(void* const* d_in, const int* in_sizes, int n_in,
                              void* d_out, int out_size, void* d_ws, size_t ws_size,
                              hipStream_t stream) {
  const float* q = (const float*)d_in[0];
  const float* k = (const float*)d_in[1];
  const float* v = (const float*)d_in[2];
  const float* pb = (const float*)d_in[3];   // [J,H]
  const float* se = (const float*)d_in[4];   // [J,HD]
  float* out = (float*)d_out;

  dim3 grid(kNWG);  // 4096 blocks, 1D, XCD-swizzled in-kernel
  dsqg_fwd<<<grid, 256, 0, stream>>>(q, k, v, pb, se, out);
}

// Round 3
// 996.416 us; speedup vs baseline: 1.7244x; 1.7244x over previous
//
#include <hip/hip_runtime.h>
#include <math.h>

namespace {

constexpr int kB = 2, kH = 16, kN = 8192, kHD = 128, kJ = 20;
constexpr int kTQ = 64;                         // queries per 256-thread block (4 lanes/query)
constexpr int kNT = kN / kTQ;                   // 128 n-tiles per (b,h)
constexpr int kNWG = kB * kH * kNT;             // 4096 workgroups
constexpr int kNXCD = 8;
constexpr int kChunk = kNWG / kNXCD;            // 512 contiguous blocks per XCD
constexpr float kScale = 0.08838834764831845f;  // 1/sqrt(128)

// Native clang vector type — required for __builtin_nontemporal_{load,store}
// (HIP_vector_type float4 is a struct and the builtin rejects it).
typedef float f4 __attribute__((ext_vector_type(4)));

// Lane mapping: t>>2 = query, t&3 = part. Lane `part` owns float4 chunks
// {i*4 + part : i in 0..7} — each wave-level load instruction covers a
// CONTIGUOUS 64B span per 4-lane group (minimum cache lines/instr).
//
// XCD swizzle: the dispatcher round-robins linear block ids across 8 XCDs.
// Without remap, consecutive n-tiles of one (b,h) slice land on different
// XCDs -> the 1024-row gather lookback misses the 4MiB per-XCD L2 and the
// ~256MiB concurrent footprint thrashes L3 (round-0: 1.26GB FETCH vs 200MB
// ideal). Remap so XCD x gets contiguous ids [x*512,(x+1)*512): 4 whole
// (b,h) slices in ascending-n order -> sliding-window reuse in L2/L3.
// Bijection: lin in [0,4096), swz=(lin&7)*512+(lin>>3).
//
// __launch_bounds__(256,4): allocator cap 128 VGPR, compiler uses 64 -> HW
// still allows 8 waves/EU.  (256,8) forced VGPR=32 and spilled rq/o to
// scratch: WRITE_SIZE 243MB->1.86GB, 2.8x slowdown (round-2 post-mortem).
__global__ __launch_bounds__(256, 4)
void dsqg_fwd(const float* __restrict__ q, const float* __restrict__ k,
              const float* __restrict__ v, const float* __restrict__ pb,
              const float* __restrict__ se, float* __restrict__ out) {
  constexpr int OFFS[kJ] = {1, 2, 3, 4, 5, 6, 7, 8, 9, 11,
                            13, 15, 16, 23, 32, 64, 128, 256, 512, 1024};
  __shared__ float s_se[kJ * kHD];  // 10 KB
  __shared__ float s_pb[kJ];

  const int t = threadIdx.x;
  const int lin = blockIdx.x;
  const int swz = (lin & (kNXCD - 1)) * kChunk + (lin >> 3);
  const int bh = swz >> 7;                  // swz / kNT
  const int ntile = swz & (kNT - 1);
  const int h = bh & (kH - 1);
  const int n = ntile * kTQ + (t >> 2);
  const int part = t & 3;

  for (int i = t; i < kJ * kHD; i += 256) s_se[i] = se[i];
  if (t < kJ) s_pb[t] = pb[t * kH + h];
  __syncthreads();

  const size_t base = (size_t)bh * kN * kHD;
  const f4* qrow = (const f4*)(q + base + (size_t)n * kHD);
  f4 rq[8];
#pragma unroll
  for (int i = 0; i < 8; ++i) rq[i] = __builtin_nontemporal_load(&qrow[i * 4 + part]);

  // ---- Phase A: s_j = sc*(q.(k[n-dj]+se_j)) + pb[j][h], -inf if n<dj
  float sc[kJ];
#pragma unroll
  for (int j = 0; j < kJ; ++j) {
    const int delta = OFFS[j];
    int kr = n - delta;
    kr = kr < 0 ? 0 : kr;
    const f4* krow = (const f4*)(k + base + (size_t)kr * kHD);
    const f4* srow = (const f4*)(s_se + j * kHD);
    float acc = 0.f;
#pragma unroll
    for (int i = 0; i < 8; ++i) {
      f4 kv = krow[i * 4 + part];
      f4 sv = srow[i * 4 + part];
      acc += rq[i].x * (kv.x + sv.x);
      acc += rq[i].y * (kv.y + sv.y);
      acc += rq[i].z * (kv.z + sv.z);
      acc += rq[i].w * (kv.w + sv.w);
    }
    acc += __shfl_xor(acc, 1);
    acc += __shfl_xor(acc, 2);
    const float sj = acc * kScale + s_pb[j];
    sc[j] = (n >= delta) ? sj : -INFINITY;
  }

  // ---- softmax over J (redundant in the 4 lanes)
  float m = -INFINITY;
#pragma unroll
  for (int j = 0; j < kJ; ++j) m = fmaxf(m, sc[j]);
  const float msafe = (m == -INFINITY) ? 0.f : m;
  float l = 0.f;
#pragma unroll
  for (int j = 0; j < kJ; ++j) {
    const float e = (sc[j] == -INFINITY) ? 0.f : __expf(sc[j] - msafe);
    sc[j] = e;  // reuse: sc now holds unnormalized p
    l += e;
  }
  const float inv = (l > 0.f) ? 1.f / l : 0.f;  // n==0 -> zero output

  // ---- Phase B: out = sum_j p_j * v[n-dj]
  f4 o[8];
#pragma unroll
  for (int i = 0; i < 8; ++i) o[i] = (f4)(0.f);
#pragma unroll
  for (int j = 0; j < kJ; ++j) {
    const float pj = sc[j] * inv;
    int vr = n - OFFS[j];
    vr = vr < 0 ? 0 : vr;
    const f4* vrow = (const f4*)(v + base + (size_t)vr * kHD);
#pragma unroll
    for (int i = 0; i < 8; ++i) {
      f4 vv = vrow[i * 4 + part];
      o[i] += pj * vv;
    }
  }
  f4* orow = (f4*)(out + base + (size_t)n * kHD);
#pragma unroll
  for (int i = 0; i < 8; ++i) __builtin_nontemporal_store(o[i], &orow[i * 4 + part]);
}

}  // namespace

extern "C" void kernel_launch(void* const* d_in, const int* in_sizes, int n_in,
                              void* d_out, int out_size, void* d_ws, size_t ws_size,
                              hipStream_t stream) {
  const float* q = (const float*)d_in[0];
  const float* k = (const float*)d_in[1];
  const float* v = (const float*)d_in[2];
  const float* pb = (const float*)d_in[3];   // [J,H]
  const float* se = (const float*)d_in[4];   // [J,HD]
  float* out = (float*)d_out;

  dim3 grid(kNWG);  // 4096 blocks, 1D, XCD-swizzled in-kernel
  dsqg_fwd<<<grid, 256, 0, stream>>>(q, k, v, pb, se, out);
}